// Round 3
// baseline (3225.146 us; speedup 1.0000x reference)
//
#include <hip/hip_runtime.h>
#include <hip/hip_bf16.h>

typedef __hip_bfloat16 bf16;
typedef unsigned short u16;

#define BATCH 512
#define CW_DIM 4096
#define DIM_CODES 64
#define BOOK_SIZE 1024
#define DIM_EMBED 64
#define ENC_H 512

__device__ __forceinline__ double lrelud(double v) { return v > 0.0 ? v : 0.2 * v; }

// dtype-agnostic loads: bf=1 -> bf16, bf=0 -> fp32 (both exact in double)
__device__ __forceinline__ float loadf(const void* p, size_t i, int bf) {
    if (bf) return __bfloat162float(((const bf16*)p)[i]);
    return ((const float*)p)[i];
}
__device__ __forceinline__ double loadd(const void* p, size_t i, int bf) {
    return (double)loadf(p, i, bf);
}
__device__ __forceinline__ void stored(void* p, size_t i, int bf, double v) {
    if (bf) ((bf16*)p)[i] = __float2bfloat16((float)v);
    else    ((float*)p)[i] = (float)v;
}

// ---------------- dtype detector ----------------
__global__ void detect_kernel(const u16* __restrict__ x, int* __restrict__ flag) {
    __shared__ int hits;
    if (threadIdx.x == 0) hits = 0;
    __syncthreads();
    int h = 0;
    for (int i = threadIdx.x; i < 16384; i += 256) {
        u16 v = x[2 * i];
        if (((v >> 7) & 0xFF) == 0xFF) h++;
    }
    atomicAdd(&hits, h);
    __syncthreads();
    if (threadIdx.x == 0) *flag = (hits == 0) ? 1 : 0;  // 1 = bf16, 0 = fp32
}

// ---------------- codebook row norms (fp64) ----------------
__global__ void booknorm_kernel(const void* __restrict__ book, double* __restrict__ bn,
                                const int* __restrict__ dflag) {
    const int bf = *dflag;
    int r = blockIdx.x * blockDim.x + threadIdx.x;
    if (r >= DIM_CODES * BOOK_SIZE) return;
    double acc = 0.0;
    for (int e = 0; e < DIM_EMBED; e++) {
        double v = loadd(book, (size_t)r * DIM_EMBED + e, bf);
        acc = fma(v, v, acc);
    }
    bn[r] = acc;
}

// ---------------- encoder conv + maxpool (fp64 accum) ----------------
__global__ __launch_bounds__(256) void enc_kernel(const void* __restrict__ x,
                                                  const void* __restrict__ w1,
                                                  const void* __restrict__ b1,
                                                  double* __restrict__ hmax,
                                                  const int* __restrict__ dflag) {
    const int bf = *dflag;
    __shared__ float xs[DIM_CODES * DIM_EMBED];  // 16 KB (exact values)
    __shared__ float wsh[256 * DIM_EMBED];       // 64 KB (exact values)
    int b = blockIdx.x, t = threadIdx.x;
    for (int i = t; i < DIM_CODES * DIM_EMBED; i += 256)
        xs[i] = loadf(x, (size_t)b * CW_DIM + i, bf);
    for (int chunk = 0; chunk < 2; ++chunk) {
        __syncthreads();
        for (int i = t; i < 256 * DIM_EMBED; i += 256)
            wsh[i] = loadf(w1, (size_t)chunk * 256 * DIM_EMBED + i, bf);
        __syncthreads();
        int h = chunk * 256 + t;
        double bias = loadd(b1, h, bf);
        double best = -1e300;
        for (int c = 0; c < DIM_CODES; c++) {
            double acc = 0.0;
            for (int e0 = 0; e0 < DIM_EMBED; e0++) {
                int e = (e0 + t) & 63;  // rotate to dodge bank pile-up
                acc = fma((double)xs[c * DIM_EMBED + e], (double)wsh[t * DIM_EMBED + e], acc);
            }
            best = fmax(best, lrelud(acc + bias));
        }
        hmax[(size_t)b * ENC_H + h] = best;
    }
}

// ---------------- fp64 GEMM: C[M,N] = act(A @ W^T + bias) ----------------
// A logically [M,Ktot]: cols [0,K1) from A1 (stride lda1), rest from A2 (stride lda2).
__global__ __launch_bounds__(256) void gemm_kernel(const double* __restrict__ A1, int lda1, int K1,
                                                   const double* __restrict__ A2, int lda2, int Ktot,
                                                   const void* __restrict__ W,
                                                   const void* __restrict__ bias,
                                                   double* __restrict__ C, int N, int act,
                                                   const int* __restrict__ dflag) {
    const int bf = *dflag;
    __shared__ double As[16][68];
    __shared__ double Ws[16][68];
    int t = threadIdx.x;
    int tx = t & 15, ty = t >> 4;
    int n0 = blockIdx.x * 64, m0 = blockIdx.y * 64;
    double acc[4][4] = {};
    for (int kt = 0; kt < Ktot; kt += 16) {
        for (int j = 0; j < 4; j++) {
            int i = t + 256 * j;
            int kk = i & 15, m = i >> 4;
            int k = kt + kk;
            double v;
            if (k < K1) v = A1[(size_t)(m0 + m) * lda1 + k];
            else        v = A2[(size_t)(m0 + m) * lda2 + (k - K1)];
            As[kk][m] = v;
        }
        for (int j = 0; j < 4; j++) {
            int i = t + 256 * j;
            int kk = i & 15, n = i >> 4;
            Ws[kk][n] = loadd(W, (size_t)(n0 + n) * Ktot + (kt + kk), bf);
        }
        __syncthreads();
        for (int kk = 0; kk < 16; kk++) {
            double a[4], w[4];
            for (int i = 0; i < 4; i++) a[i] = As[kk][ty * 4 + i];
            for (int i = 0; i < 4; i++) w[i] = Ws[kk][tx * 4 + i];
            for (int i = 0; i < 4; i++)
                for (int j = 0; j < 4; j++) acc[i][j] = fma(a[i], w[j], acc[i][j]);
        }
        __syncthreads();
    }
    for (int i = 0; i < 4; i++) {
        int m = m0 + ty * 4 + i;
        for (int j = 0; j < 4; j++) {
            int n = n0 + tx * 4 + j;
            double v = acc[i][j] + loadd(bias, n, bf);
            if (act) v = lrelud(v);
            C[(size_t)m * N + n] = v;
        }
    }
}

// ---------------- z2 = dfull[:, :768] + pfull[:, :768] ----------------
__global__ void add_kernel(const double* __restrict__ a, int lda_a,
                           const double* __restrict__ b, int lda_b,
                           double* __restrict__ o, int ncol, int total) {
    int i = blockIdx.x * blockDim.x + threadIdx.x;
    if (i >= total) return;
    int m = i / ncol, j = i % ncol;
    o[i] = a[(size_t)m * lda_a + j] + b[(size_t)m * lda_b + j];
}

// ---------------- strided fp64 -> output-dtype cast ----------------
__global__ void cast_kernel(const double* __restrict__ src, int lda, int col0, int ncol,
                            void* __restrict__ out, size_t obase, int total,
                            const int* __restrict__ dflag) {
    const int bf = *dflag;
    int i = blockIdx.x * blockDim.x + threadIdx.x;
    if (i >= total) return;
    int m = i / ncol, j = i % ncol;
    stored(out, obase + i, bf, src[(size_t)m * lda + col0 + j]);
}

// ---------------- fused cw_dist (fp64) + exact argmin, no atomics ----------------
// grid (c=64, btile=16); block 256 = 4 waves. Block covers 32 b-rows x all 1024 s.
__global__ __launch_bounds__(256) void dist_kernel(const double* __restrict__ cwr,
                                                   const void* __restrict__ book,
                                                   const double* __restrict__ bn,
                                                   void* __restrict__ out,
                                                   size_t odist, size_t oidx,
                                                   const int* __restrict__ dflag) {
    const int bf = *dflag;
    __shared__ double xs[32][64];   // 16 KB
    __shared__ double xn[32];
    __shared__ float bs[64][65];    // padded: bank = (sl + e) & 31, conflict-free
    int t = threadIdx.x;
    int c = blockIdx.x;
    int b0 = blockIdx.y * 32;
    int sl = t & 63, wv = t >> 6;

    for (int i = t; i < 32 * 64; i += 256) {
        int bl = i >> 6, e = i & 63;
        xs[bl][e] = cwr[(size_t)(b0 + bl) * CW_DIM + c * DIM_EMBED + e];
    }
    __syncthreads();
    if (t < 32) {
        double a = 0.0;
        for (int e = 0; e < 64; e++) a = fma(xs[t][e], xs[t][e], a);
        xn[t] = a;
    }

    double bd[8];
    int bsx[8];
#pragma unroll
    for (int p = 0; p < 8; p++) { bd[p] = 1e300; bsx[p] = 0; }

    for (int st = 0; st < 16; st++) {
        int s0 = st * 64;
        __syncthreads();  // previous-tile readers done (and xn visible on st==0)
        for (int i = t; i < 64 * 64; i += 256) {
            int srow = i >> 6, e = i & 63;
            bs[srow][e] = loadf(book, ((size_t)c * BOOK_SIZE + s0 + srow) * DIM_EMBED + e, bf);
        }
        __syncthreads();
        double bnv = bn[(size_t)c * BOOK_SIZE + s0 + sl];
#pragma unroll
        for (int p = 0; p < 8; p++) {
            int bl = wv * 8 + p;
            double acc = 0.0;
#pragma unroll
            for (int e = 0; e < 64; e++)
                acc = fma(xs[bl][e], (double)bs[sl][e], acc);
            double d = xn[bl] + bnv - 2.0 * acc;
            stored(out, odist + ((size_t)(b0 + bl) * DIM_CODES + c) * BOOK_SIZE + s0 + sl, bf, d);
            if (d < bd[p]) { bd[p] = d; bsx[p] = s0 + sl; }
        }
    }
#pragma unroll
    for (int p = 0; p < 8; p++) {
        double d = bd[p];
        int s = bsx[p];
        for (int off = 32; off >= 1; off >>= 1) {
            double od = __shfl_xor(d, off, 64);
            int os = __shfl_xor(s, off, 64);
            if (od < d || (od == d && os < s)) { d = od; s = os; }
        }
        if (sl == 0)
            stored(out, oidx + (size_t)(b0 + wv * 8 + p) * DIM_CODES + c, bf, (double)s);
    }
}

extern "C" void kernel_launch(void* const* d_in, const int* in_sizes, int n_in,
                              void* d_out, int out_size, void* d_ws, size_t ws_size,
                              hipStream_t stream) {
    const void* x        = d_in[0];
    const void* codebook = d_in[1];
    const void* enc_w1   = d_in[2];
    const void* enc_b1   = d_in[3];
    const void* enc_w2   = d_in[4];
    const void* enc_b2   = d_in[5];
    const void* inf1_w   = d_in[6];
    const void* inf1_b   = d_in[7];
    const void* inf2_w1  = d_in[8];
    const void* inf2_b1  = d_in[9];
    const void* inf2_w2  = d_in[10];
    const void* inf2_b2  = d_in[11];
    const void* prior_w1 = d_in[12];
    const void* prior_b1 = d_in[13];
    const void* prior_w2 = d_in[14];
    const void* prior_b2 = d_in[15];
    const void* dec_w1   = d_in[16];
    const void* dec_b1   = d_in[17];
    const void* dec_w2   = d_in[18];
    const void* dec_b2   = d_in[19];

    // ---- fp64 workspace with aliasing (total ~52 MB) ----
    double* W = (double*)d_ws;
    double* inf1out = W;                   // 512*512           [live to end]
    double* pfull   = inf1out + 262144;    // 512*1536          [live to end]
    double* dfull   = pfull + 786432;      // 512*1536          [live to end]
    double* cwr     = dfull + 786432;      // 512*4096          [live to end]
    double* bn      = cwr + 2097152;       // 64*1024
    double* bufA    = bn + 65536;          // 512*2048: h2, later dech
    double* bufB    = bufA + 1048576;      // 512*2048: p1, later d1
    double* bufC    = bufB + 1048576;      // 512*768: hmax(512*512), later z2
    int* dflag      = (int*)(bufC + 393216);

    // ---- output slice element offsets (return order) ----
    const size_t o_cwrecon = 0;
    const size_t o_cwdist  = 2097152;
    const size_t o_idx     = 35651584;
    const size_t o_mu      = 35684352;
    const size_t o_logvar  = 35815424;
    const size_t o_dmu     = 35946496;
    const size_t o_dlogvar = 36339712;
    const size_t o_plogvar = 36732928;

    detect_kernel<<<1, 256, 0, stream>>>((const u16*)x, dflag);
    booknorm_kernel<<<256, 256, 0, stream>>>(codebook, bn, dflag);
    enc_kernel<<<BATCH, 256, 0, stream>>>(x, enc_w1, enc_b1, bufC, dflag);  // hmax -> bufC

    // h2 = hmax @ enc_w2^T
    gemm_kernel<<<dim3(32, 8), 256, 0, stream>>>(bufC, 512, 512, bufC, 512, 512,
                                                 enc_w2, enc_b2, bufA, 2048, 0, dflag);
    // inf1out = h2 @ inf1_w^T (mu | log_var)
    gemm_kernel<<<dim3(8, 8), 256, 0, stream>>>(bufA, 2048, 2048, bufA, 2048, 2048,
                                                inf1_w, inf1_b, inf1out, 512, 0, dflag);
    // p1 = lrelu(z1 @ prior_w1^T); z1 = inf1out[:, :256]
    gemm_kernel<<<dim3(32, 8), 256, 0, stream>>>(inf1out, 512, 256, inf1out, 512, 256,
                                                 prior_w1, prior_b1, bufB, 2048, 1, dflag);
    // pfull = p1 @ prior_w2^T
    gemm_kernel<<<dim3(24, 8), 256, 0, stream>>>(bufB, 2048, 2048, bufB, 2048, 2048,
                                                 prior_w2, prior_b2, pfull, 1536, 0, dflag);
    // d1 = lrelu(concat(z1, h2) @ inf2_w1^T)   (overwrites p1, dead)
    gemm_kernel<<<dim3(32, 8), 256, 0, stream>>>(inf1out, 512, 256, bufA, 2048, 2304,
                                                 inf2_w1, inf2_b1, bufB, 2048, 1, dflag);
    // dfull = d1 @ inf2_w2^T
    gemm_kernel<<<dim3(24, 8), 256, 0, stream>>>(bufB, 2048, 2048, bufB, 2048, 2048,
                                                 inf2_w2, inf2_b2, dfull, 1536, 0, dflag);
    // z2 = dfull[:, :768] + pfull[:, :768]   (hmax dead -> bufC)
    add_kernel<<<1536, 256, 0, stream>>>(dfull, 1536, pfull, 1536, bufC, 768, 393216);
    // dech = lrelu(z2 @ dec_w1^T)   (h2 dead -> bufA)
    gemm_kernel<<<dim3(32, 8), 256, 0, stream>>>(bufC, 768, 768, bufC, 768, 768,
                                                 dec_w1, dec_b1, bufA, 2048, 1, dflag);
    // cwr = dech @ dec_w2^T
    gemm_kernel<<<dim3(64, 8), 256, 0, stream>>>(bufA, 2048, 2048, bufA, 2048, 2048,
                                                 dec_w2, dec_b2, cwr, 4096, 0, dflag);

    // fused distances + argmin (writes o_cwdist and o_idx directly)
    dist_kernel<<<dim3(64, 16), 256, 0, stream>>>(cwr, codebook, bn,
                                                  d_out, o_cwdist, o_idx, dflag);

    // output casts
    cast_kernel<<<8192, 256, 0, stream>>>(cwr, 4096, 0, 4096, d_out, o_cwrecon, 2097152, dflag);
    cast_kernel<<<512, 256, 0, stream>>>(inf1out, 512, 0, 256, d_out, o_mu, 131072, dflag);
    cast_kernel<<<512, 256, 0, stream>>>(inf1out, 512, 256, 256, d_out, o_logvar, 131072, dflag);
    cast_kernel<<<1536, 256, 0, stream>>>(dfull, 1536, 0, 768, d_out, o_dmu, 393216, dflag);
    cast_kernel<<<1536, 256, 0, stream>>>(dfull, 1536, 768, 768, d_out, o_dlogvar, 393216, dflag);
    cast_kernel<<<1536, 256, 0, stream>>>(pfull, 1536, 768, 768, d_out, o_plogvar, 393216, dflag);
}